// Round 1
// baseline (110.479 us; speedup 1.0000x reference)
//
#include <hip/hip_runtime.h>
#include <hip/hip_bf16.h>

// Problem: out[b,m,n] = sum_k fq(x1)[b,m,k] * fq(x2)[b,k,n]
// B=8, M=4096, K=64, N=4096. fq = PACT fake-quant: clamp[0,c], round to
// level=256 uniform levels -> every value is code/255 with code in [0,255].
// Codes are exact in bf16 -> exact integer MFMA GEMM, scale at the end.
// Roofline: 512MB output write -> ~85us at 6.3 TB/s. Write-bound.

#define BATCH 8
#define MDIM 4096
#define KDIM 64
#define NDIM 4096

typedef __attribute__((ext_vector_type(4))) unsigned short u16x4;
typedef __attribute__((ext_vector_type(8))) short s16x8;
typedef __attribute__((ext_vector_type(4))) float f32x4;

// quantize x -> integer code (0..level-1) as bf16 bit pattern (exact:
// integers 0..255 fit in bf16's 8 significand bits, low f32 mantissa = 0)
__device__ __forceinline__ unsigned short qcode(float x, float c, float inv) {
    float xc = fminf(fmaxf(x, 0.0f), c);
    float k = rintf(xc * inv);            // round-half-even, matches np.round
    return (unsigned short)(__float_as_uint(k) >> 16);
}

// ---- kernel 1: elementwise quantize x1 [B,M,K] -> bf16 codes (same layout)
__global__ void quantA_k(const float* __restrict__ x, unsigned short* __restrict__ q,
                         const float* __restrict__ clip, const int* __restrict__ level,
                         int n4) {
    float c = clip[0];
    float inv = (float)(level[0] - 1) / c;
    int i = blockIdx.x * 256 + threadIdx.x;
    if (i >= n4) return;
    float4 v = ((const float4*)x)[i];
    u16x4 o;
    o[0] = qcode(v.x, c, inv);
    o[1] = qcode(v.y, c, inv);
    o[2] = qcode(v.z, c, inv);
    o[3] = qcode(v.w, c, inv);
    ((u16x4*)q)[i] = o;
}

// ---- kernel 2: quantize + transpose x2 [B,K,N] -> bf16 codes [B,N,K]
// (both GEMM operands become K-contiguous). 64x64 tile through LDS.
__global__ void quantB_t(const float* __restrict__ x, unsigned short* __restrict__ q,
                         const float* __restrict__ clip, const int* __restrict__ level) {
    __shared__ unsigned short T[64 * 68];   // pad 68 to spread banks
    int b = blockIdx.y;
    int n0 = blockIdx.x * 64;
    float c = clip[0];
    float inv = (float)(level[0] - 1) / c;
    int t = threadIdx.x;

    const float* src = x + (size_t)b * KDIM * NDIM + n0;
#pragma unroll
    for (int it = 0; it < 4; ++it) {
        int qi = t + it * 256;
        int k = qi >> 4, c4 = qi & 15;          // 64 rows x 16 float4
        float4 v = *(const float4*)(src + (size_t)k * NDIM + c4 * 4);
        u16x4 o;
        o[0] = qcode(v.x, c, inv);
        o[1] = qcode(v.y, c, inv);
        o[2] = qcode(v.z, c, inv);
        o[3] = qcode(v.w, c, inv);
        *(u16x4*)&T[k * 68 + c4 * 4] = o;
    }
    __syncthreads();

    unsigned short* dst = q + ((size_t)b * NDIM + n0) * KDIM;
#pragma unroll
    for (int it = 0; it < 4; ++it) {
        int qi = t + it * 256;
        int n = qi >> 4, c4 = qi & 15;          // 64 out-rows x 16 chunks of 4
        u16x4 o;
        o[0] = T[(c4 * 4 + 0) * 68 + n];
        o[1] = T[(c4 * 4 + 1) * 68 + n];
        o[2] = T[(c4 * 4 + 2) * 68 + n];
        o[3] = T[(c4 * 4 + 3) * 68 + n];
        *(u16x4*)(dst + (size_t)n * KDIM + c4 * 4) = o;
    }
}

// ---- kernel 3: GEMM. 128x128 tile, full K=64 staged once, 4 waves (2x2),
// each wave 64x64 via 4x4 grid of 16x16x32 bf16 MFMA fragments.
__global__ __launch_bounds__(256)
void gemm_q(const unsigned short* __restrict__ qA, const unsigned short* __restrict__ qBt,
            const float* __restrict__ c1p, const float* __restrict__ c2p,
            const int* __restrict__ lvp, float* __restrict__ out) {
    __shared__ unsigned short As[128 * 64];   // 16KB, XOR-swizzled addressing
    __shared__ unsigned short Bs[128 * 64];   // holds B^T tile: rows = n

    const int b = blockIdx.z, mt = blockIdx.y, nt = blockIdx.x;
    const int t = threadIdx.x;

    const unsigned short* gA = qA + ((size_t)b * MDIM + mt * 128) * KDIM;
    const unsigned short* gB = qBt + ((size_t)b * NDIM + nt * 128) * KDIM;

    // stage both tiles: 128 rows x 128B, 16B per thread-iter, swizzle rows
#pragma unroll
    for (int it = 0; it < 4; ++it) {
        int qi = t + it * 256;
        int row = qi >> 3, c8 = qi & 7;
        s16x8 va = *(const s16x8*)(gA + (size_t)row * KDIM + c8 * 8);
        s16x8 vb = *(const s16x8*)(gB + (size_t)row * KDIM + c8 * 8);
        int off = (row * 128 + c8 * 16) ^ ((row & 7) << 4);
        *(s16x8*)((char*)As + off) = va;
        *(s16x8*)((char*)Bs + off) = vb;
    }
    __syncthreads();

    const int lane = t & 63, w = t >> 6;
    const int wr = (w >> 1) * 64, wc = (w & 1) * 64;   // wave 64x64 sub-tile
    const int r16 = lane & 15, kq = lane >> 4;

    f32x4 acc[4][4] = {};
#pragma unroll
    for (int ks = 0; ks < 2; ++ks) {
        const int kb = ks * 64 + kq * 16;   // byte offset of this lane's k-slice
        s16x8 a[4], bf[4];
#pragma unroll
        for (int mf = 0; mf < 4; ++mf) {
            int row = wr + mf * 16 + r16;
            int off = (row * 128 + kb) ^ ((row & 7) << 4);
            a[mf] = *(const s16x8*)((const char*)As + off);
        }
#pragma unroll
        for (int nf = 0; nf < 4; ++nf) {
            int row = wc + nf * 16 + r16;
            int off = (row * 128 + kb) ^ ((row & 7) << 4);
            bf[nf] = *(const s16x8*)((const char*)Bs + off);
        }
#pragma unroll
        for (int mf = 0; mf < 4; ++mf)
#pragma unroll
            for (int nf = 0; nf < 4; ++nf)
                acc[mf][nf] = __builtin_amdgcn_mfma_f32_16x16x32_bf16(
                    a[mf], bf[nf], acc[mf][nf], 0, 0, 0);
    }

    // epilogue: scale integer-code accum by scale1*scale2, store f32
    float c1 = c1p[0], c2 = c2p[0];
    float lvm1 = (float)(lvp[0] - 1);
    float s = (c1 / lvm1) * (c2 / lvm1);

    size_t obase = (size_t)b * MDIM * NDIM;
    int m0 = mt * 128 + wr, n0 = nt * 128 + wc;
#pragma unroll
    for (int mf = 0; mf < 4; ++mf) {
#pragma unroll
        for (int i = 0; i < 4; ++i) {
            int m = m0 + mf * 16 + kq * 4 + i;
            float* orow = out + obase + (size_t)m * NDIM + n0 + r16;
#pragma unroll
            for (int nf = 0; nf < 4; ++nf)
                orow[nf * 16] = acc[mf][nf][i] * s;
        }
    }
}

extern "C" void kernel_launch(void* const* d_in, const int* in_sizes, int n_in,
                              void* d_out, int out_size, void* d_ws, size_t ws_size,
                              hipStream_t stream) {
    const float* x1 = (const float*)d_in[0];
    const float* x2 = (const float*)d_in[1];
    const float* c1 = (const float*)d_in[2];
    const float* c2 = (const float*)d_in[3];
    const int* lv   = (const int*)d_in[4];
    float* out = (float*)d_out;

    // workspace: qA codes 4MB @ 0, qB^T codes 4MB @ +4MB (needs ws >= 8MB)
    unsigned short* qA = (unsigned short*)d_ws;
    unsigned short* qB = qA + (size_t)BATCH * MDIM * KDIM;

    quantA_k<<<(BATCH * MDIM * KDIM / 4 + 255) / 256, 256, 0, stream>>>(
        x1, qA, c1, lv, BATCH * MDIM * KDIM / 4);
    quantB_t<<<dim3(NDIM / 64, BATCH), 256, 0, stream>>>(x2, qB, c2, lv);
    gemm_q<<<dim3(NDIM / 128, MDIM / 128, BATCH), 256, 0, stream>>>(
        qA, qB, c1, c2, lv, out);
}